// Round 10
// baseline (173.759 us; speedup 1.0000x reference)
//
#include <hip/hip_runtime.h>
#include <stdint.h>
#include <math.h>

// OptimalTransportLoss: b=64 pairs^2, n=128, d=128.
// ws floats: [0]=cost_min, [1]=cost_span, [2..8193]=per-block sq min/max pairs,
//            [8194..12289]=distances per (i,j) block.
//
// LDS (bytes): [0,16384) eL (128 rows x 32 u32 fp16-pairs, d-half)  } overlaid
//              [16384,32768) tL                                     } by Kh
//              [32768,33280) e2a | [33280,33792) t2a
//   phaseA: [33792,33824) red                       -> 33824 total
//   phaseC: [33792,34048) vh2 | [34048,34304) uh2 | [34304,34336) red -> 34336

typedef _Float16 h2 __attribute__((ext_vector_type(2)));
typedef _Float16 h8v __attribute__((ext_vector_type(8)));
typedef float f4v __attribute__((ext_vector_type(4)));

__device__ __forceinline__ h2 bch2(uint32_t u) { return __builtin_bit_cast(h2, u); }
__device__ __forceinline__ uint32_t pkh2(float x, float y) {
  h2 h = {(_Float16)x, (_Float16)y};
  return __builtin_bit_cast(uint32_t, h);
}
__device__ __forceinline__ float rnd16(float x) { return (float)(_Float16)x; }
__device__ __forceinline__ float fdot2f(h2 a, h2 b, float c) {
  return __builtin_amdgcn_fdot2(a, b, c, false);
}
// per-row LDS swizzle (u32-index XOR within a 32-u32 row): optimal b128 frag reads
__device__ __forceinline__ int swz(int r) { return ((r & 7) << 2) ^ ((r & 8) << 1); }

// Stage d-half p (cols 64p..64p+63) of eeg[i], text[j] into LDS as fp16 pairs.
__device__ __forceinline__ void stageHalf(const float* __restrict__ ep,
                                          const float* __restrict__ tp,
                                          uint32_t* eL, uint32_t* tL, int t, int p) {
  const float4* e4 = (const float4*)ep;
  const float4* t4 = (const float4*)tp;
#pragma unroll
  for (int k = 0; k < 8; ++k) {
    int F = k * 256 + t;          // 0..2047
    int m = F >> 4, g = F & 15;   // row, float4-group within half
    int src = m * 32 + 16 * p + g;
    int idx = m * 32 + ((2 * g) ^ swz(m));   // even; +1 adjacent (swz has no bit0)
    float4 x = e4[src];
    *(uint2*)(eL + idx) = make_uint2(pkh2(x.x, x.y), pkh2(x.z, x.w));
    float4 y = t4[src];
    *(uint2*)(tL + idx) = make_uint2(pkh2(y.x, y.y), pkh2(y.z, y.w));
  }
}

// fp16 squared-norm partial for this thread's row over one half (order-stable).
__device__ __forceinline__ void normPartial(const uint32_t* eL, const uint32_t* tL,
                                            int t, float& a0, float& a1) {
  int r = t & 127;
  const uint32_t* base = ((t < 128) ? eL : tL) + r * 32;
  int sw = swz(r);
#pragma unroll
  for (int kl = 0; kl < 16; ++kl) {
    uint2 u = *(const uint2*)(base + ((2 * kl) ^ sw));
    h2 x = bch2(u.x), y = bch2(u.y);
    a0 = fdot2f(x, x, a0);
    a1 = fdot2f(y, y, a1);
  }
}

// MFMA build over one d-half (2 k-steps of 32). Wave w owns C rows 32w..32w+31.
// C/D map (m89-verified): value j of acc -> row 16*(2w+i)+4*lg+j, col 16*tc+lr.
__device__ __forceinline__ void buildMfma(const uint32_t* eL, const uint32_t* tL,
                                          int w, int lr, int lg, f4v (&acc)[2][8]) {
#pragma unroll
  for (int ks = 0; ks < 2; ++ks) {
    int off = ks * 16 + lg * 4;
    int r0 = 32 * w + lr, r1 = r0 + 16;
    h8v A0 = *(const h8v*)(eL + r0 * 32 + (off ^ swz(r0)));
    h8v A1 = *(const h8v*)(eL + r1 * 32 + (off ^ swz(r1)));
#pragma unroll
    for (int tg = 0; tg < 2; ++tg) {
      h8v B[4];
#pragma unroll
      for (int q = 0; q < 4; ++q) {
        int rt = (4 * tg + q) * 16 + lr;
        B[q] = *(const h8v*)(tL + rt * 32 + (off ^ swz(rt)));
      }
#pragma unroll
      for (int q = 0; q < 4; ++q) {
        acc[0][4 * tg + q] = __builtin_amdgcn_mfma_f32_16x16x32_f16(A0, B[q], acc[0][4 * tg + q], 0, 0, 0);
        acc[1][4 * tg + q] = __builtin_amdgcn_mfma_f32_16x16x32_f16(A1, B[q], acc[1][4 * tg + q], 0, 0, 0);
      }
    }
  }
}

// ---------------- Phase A: per-block min/max of sq (pre-sqrt, monotone) -------------
// waves_per_eu(3,4): 64 AGPR acc + ~100 arch VGPR fits the 170-reg budget, no spill.
__attribute__((amdgpu_waves_per_eu(3, 4)))
__global__ __launch_bounds__(256) void phaseA(const float* __restrict__ eeg,
                                              const float* __restrict__ text,
                                              float* __restrict__ ws) {
  extern __shared__ char smem[];
  uint32_t* eL = (uint32_t*)smem;
  uint32_t* tL = (uint32_t*)(smem + 16384);
  float* e2a   = (float*)(smem + 32768);
  float* t2a   = (float*)(smem + 33280);
  float* red   = (float*)(smem + 33792);
  int t = threadIdx.x, b = blockIdx.x;
  const float* ep = eeg + (size_t)(b >> 6) * 16384;
  const float* tp = text + (size_t)(b & 63) * 16384;

  int w = t >> 6, lr = t & 15, lg = (t >> 4) & 3;
  f4v acc[2][8];
#pragma unroll
  for (int i = 0; i < 2; ++i)
#pragma unroll
    for (int tc = 0; tc < 8; ++tc) acc[i][tc] = (f4v){0.f, 0.f, 0.f, 0.f};
  float na0 = 0.f, na1 = 0.f;

  stageHalf(ep, tp, eL, tL, t, 0);
  __syncthreads();
  normPartial(eL, tL, t, na0, na1);
  buildMfma(eL, tL, w, lr, lg, acc);
  __syncthreads();
  stageHalf(ep, tp, eL, tL, t, 1);
  __syncthreads();
  normPartial(eL, tL, t, na0, na1);
  {
    int r = t & 127;
    float nn = rnd16(na0 + na1);
    if (t < 128) e2a[r] = nn; else t2a[r] = nn;
  }
  buildMfma(eL, tL, w, lr, lg, acc);
  __syncthreads();

  float e2x[2][4], t2x[8];
#pragma unroll
  for (int i = 0; i < 2; ++i)
#pragma unroll
    for (int j = 0; j < 4; ++j) e2x[i][j] = e2a[32 * w + 16 * i + 4 * lg + j];
#pragma unroll
  for (int tc = 0; tc < 8; ++tc) t2x[tc] = t2a[16 * tc + lr];

  float smn = 1e30f, smx = -1e30f;
#pragma unroll
  for (int i = 0; i < 2; ++i)
#pragma unroll
    for (int tc = 0; tc < 8; ++tc)
#pragma unroll
      for (int j = 0; j < 4; ++j) {
        float ip = rnd16(acc[i][tc][j]);
        float sq = fmaxf(fmaf(-2.0f, ip, e2x[i][j] + t2x[tc]), 0.0f);
        smn = fminf(smn, sq);
        smx = fmaxf(smx, sq);
      }
#pragma unroll
  for (int msk = 1; msk < 64; msk <<= 1) {
    smn = fminf(smn, __shfl_xor(smn, msk));
    smx = fmaxf(smx, __shfl_xor(smx, msk));
  }
  if ((t & 63) == 0) { red[t >> 6] = smn; red[4 + (t >> 6)] = smx; }
  __syncthreads();
  if (t == 0) {
    float mn = fminf(fminf(red[0], red[1]), fminf(red[2], red[3]));
    float mx = fmaxf(fmaxf(red[4], red[5]), fmaxf(red[6], red[7]));
    ws[2 + 2 * b] = mn;   // per-block plain writes: no atomic contention (round-7 lesson)
    ws[3 + 2 * b] = mx;
  }
}

// ---------------- Phase B: reduce 4096 block min/max -> cost_min, cost_span ---------
__global__ void phaseB(float* __restrict__ ws) {
  __shared__ float red[16];
  int t = threadIdx.x;
  float mn = 1e30f, mx = -1e30f;
#pragma unroll
  for (int k = 0; k < 16; ++k) {
    int idx = k * 256 + t;
    mn = fminf(mn, ws[2 + 2 * idx]);
    mx = fmaxf(mx, ws[3 + 2 * idx]);
  }
#pragma unroll
  for (int msk = 1; msk < 64; msk <<= 1) {
    mn = fminf(mn, __shfl_xor(mn, msk));
    mx = fmaxf(mx, __shfl_xor(mx, msk));
  }
  if ((t & 63) == 0) { red[t >> 6] = mn; red[8 + (t >> 6)] = mx; }
  __syncthreads();
  if (t == 0) {
    mn = fminf(fminf(red[0], red[1]), fminf(red[2], red[3]));
    mx = fmaxf(fmaxf(red[8], red[9]), fmaxf(red[10], red[11]));
    float cmn = rnd16(sqrtf(rnd16(mn)));
    float cmx = rnd16(sqrtf(rnd16(mx)));
    ws[0] = cmn;
    ws[1] = cmx - cmn;
  }
}

// ---- hot-loop helper macros (named registers only, no private arrays) --------------
#define FD(A, V, ACC) ACC = fdot2f(bch2(A), bch2(V), ACC);
#define GK(KI, CV, DV) { \
    int r0_ = 32 * bq + 2 * (KI); int rh_ = 16 * bq + (KI); \
    uint32_t g0_ = Kh[r0_ * 64 + (((cgk + rh_) & 15) * 4 + pos4)]; \
    uint32_t g1_ = Kh[(r0_ + 1) * 64 + (((cgk + rh_) & 15) * 4 + pos4)]; \
    CV = __builtin_amdgcn_perm(g1_, g0_, 0x05040100u); \
    DV = __builtin_amdgcn_perm(g1_, g0_, 0x07060302u); }
#define DST(AK, BK, VK) { \
    h2 vp_ = bch2(VK), K0_ = bch2(AK), K1_ = bch2(BK); float kf_, vf_; \
    kf_ = (float)K0_[0]; vf_ = (float)vp_[0]; acc0 += kf_ * vf_ * (8.0f - __log2f(kf_)); \
    kf_ = (float)K0_[1]; vf_ = (float)vp_[1]; acc0 += kf_ * vf_ * (8.0f - __log2f(kf_)); \
    kf_ = (float)K1_[0]; vf_ = (float)vp_[0]; acc1 += kf_ * vf_ * (8.0f - __log2f(kf_)); \
    kf_ = (float)K1_[1]; vf_ = (float)vp_[1]; acc1 += kf_ * vf_ * (8.0f - __log2f(kf_)); }

// ---------------- Phase C: MFMA cost build + register-resident OR-Sinkhorn ----------
// K' = 2^8 * exp(-(c-cmn)/(0.1*span)) stored fp16 (all normal: [0.0116,256]).
// Over-relaxed updates u <- u*(u*Kv)^{-omega} share the reference map's UNIQUE fixed
// point (omega in (0,2)); exit certificate max|colsum-1| < 4e-3 bounds distance to the
// fixed point identically to plain iteration, and the reference's 100 plain iters are
// at that fixed point (measured: plain converges by ~23 iters, dev then ~0 by 100).
// First 2 iters run omega=1 to settle the raw transient; cap 100 guards worst case.
__attribute__((amdgpu_waves_per_eu(3, 4)))
__global__ __launch_bounds__(256) void phaseC(const float* __restrict__ eeg,
                                              const float* __restrict__ text,
                                              float* __restrict__ ws) {
  extern __shared__ char smem[];
  uint32_t* eL  = (uint32_t*)smem;
  uint32_t* tL  = (uint32_t*)(smem + 16384);
  uint32_t* Kh  = (uint32_t*)smem;              // 8192 u32 overlay
  float* e2a    = (float*)(smem + 32768);
  float* t2a    = (float*)(smem + 33280);
  uint32_t* vh2 = (uint32_t*)(smem + 33792);
  uint32_t* uh2 = (uint32_t*)(smem + 34048);
  float* red    = (float*)(smem + 34304);
  int t = threadIdx.x, b = blockIdx.x;
  const float* ep = eeg + (size_t)(b >> 6) * 16384;
  const float* tp = text + (size_t)(b & 63) * 16384;

  int w = t >> 6, lr = t & 15, lg = (t >> 4) & 3;
  f4v acc[2][8];
#pragma unroll
  for (int i = 0; i < 2; ++i)
#pragma unroll
    for (int tc = 0; tc < 8; ++tc) acc[i][tc] = (f4v){0.f, 0.f, 0.f, 0.f};
  float na0 = 0.f, na1 = 0.f;

  stageHalf(ep, tp, eL, tL, t, 0);
  __syncthreads();
  normPartial(eL, tL, t, na0, na1);
  buildMfma(eL, tL, w, lr, lg, acc);
  __syncthreads();
  stageHalf(ep, tp, eL, tL, t, 1);
  __syncthreads();
  normPartial(eL, tL, t, na0, na1);
  {
    int r = t & 127;
    float nn = rnd16(na0 + na1);
    if (t < 128) e2a[r] = nn; else t2a[r] = nn;
  }
  buildMfma(eL, tL, w, lr, lg, acc);
  __syncthreads();   // eL/tL reads done; e2a/t2a visible; Kh overlay now safe

  float cmn = ws[0];
  float kexp2 = 1.4426950408889634f / (0.1f * ws[1]);  // log2e/(reg*span)

  float e2x[2][4], t2x[8];
#pragma unroll
  for (int i = 0; i < 2; ++i)
#pragma unroll
    for (int j = 0; j < 4; ++j) e2x[i][j] = e2a[32 * w + 16 * i + 4 * lg + j];
#pragma unroll
  for (int tc = 0; tc < 8; ++tc) t2x[tc] = t2a[16 * tc + lr];

  // K-build: per element -> fp16 bits into Kh with rotation swizzle
  //   pos(hc,row) = (((hc>>2)+(row>>1))&15)*4 + (hc&3), hc = col>>1
  uint16_t* Kh16 = (uint16_t*)Kh;
  float ks = 0.f;
#pragma unroll
  for (int i = 0; i < 2; ++i)
#pragma unroll
    for (int tc = 0; tc < 8; ++tc)
#pragma unroll
      for (int j = 0; j < 4; ++j) {
        int row = 32 * w + 16 * i + 4 * lg + j;
        int col = 16 * tc + lr;
        float ip = rnd16(acc[i][tc][j]);
        float sq = fmaxf(fmaf(-2.0f, ip, e2x[i][j] + t2x[tc]), 0.0f);
        float c  = rnd16(sqrtf(rnd16(sq)));
        float kf = exp2f(fmaf(cmn - c, kexp2, 8.0f));   // 2^8-scaled kernel
        ks += kf;
        int hc = col >> 1;
        int pos = (((hc >> 2) + (row >> 1)) & 15) * 4 + (hc & 3);
        Kh16[(row * 64 + pos) * 2 + (col & 1)] = __builtin_bit_cast(uint16_t, (_Float16)kf);
      }
#pragma unroll
  for (int msk = 1; msk < 64; msk <<= 1) ks += __shfl_xor(ks, msk);
  if ((t & 63) == 0) red[t >> 6] = ks;
  __syncthreads();
  float Sp = (red[0] + red[1]) + (red[2] + red[3]);   // = 256 * sum(K)
  float uinit = 256.0f / Sp;                           // = 1/sum(K)
  if (t < 64) { vh2[t] = 0x3C003C00u; uh2[t] = pkh2(uinit, uinit); }

  // Register K tiles as NAMED registers.
  // Lane (w,la,bq): rows n0,n0+1 (aN/bN), cols 2nh,2nh+1 (cN/dN).
  int l = t & 63, la = l >> 2, bq = l & 3;
  int n0 = 32 * w + 2 * la;
  int nh = 16 * w + la;
  int cgk = nh >> 2, pos4 = la & 3;
  uint32_t a0,a1,a2,a3,a4,a5,a6,a7,a8,a9,aa,ab,ac,ad,ae,af;
  uint32_t b0,b1,b2,b3,b4,b5,b6,b7,b8,b9,ba,bb,bc,bd,be,bf;
  {
    int g0 = (4 * bq + 0 + nh) & 15, g1 = (4 * bq + 1 + nh) & 15;
    int g2 = (4 * bq + 2 + nh) & 15, g3 = (4 * bq + 3 + nh) & 15;
    uint4 X;
    X = *(const uint4*)(Kh + n0 * 64 + g0 * 4); a0 = X.x; a1 = X.y; a2 = X.z; a3 = X.w;
    X = *(const uint4*)(Kh + n0 * 64 + g1 * 4); a4 = X.x; a5 = X.y; a6 = X.z; a7 = X.w;
    X = *(const uint4*)(Kh + n0 * 64 + g2 * 4); a8 = X.x; a9 = X.y; aa = X.z; ab = X.w;
    X = *(const uint4*)(Kh + n0 * 64 + g3 * 4); ac = X.x; ad = X.y; ae = X.z; af = X.w;
    X = *(const uint4*)(Kh + (n0 + 1) * 64 + g0 * 4); b0 = X.x; b1 = X.y; b2 = X.z; b3 = X.w;
    X = *(const uint4*)(Kh + (n0 + 1) * 64 + g1 * 4); b4 = X.x; b5 = X.y; b6 = X.z; b7 = X.w;
    X = *(const uint4*)(Kh + (n0 + 1) * 64 + g2 * 4); b8 = X.x; b9 = X.y; ba = X.z; bb = X.w;
    X = *(const uint4*)(Kh + (n0 + 1) * 64 + g3 * 4); bc = X.x; bd = X.y; be = X.z; bf = X.w;
  }
  uint32_t c0,c1,c2,c3,c4,c5,c6,c7,c8,c9,ca,cb,cc,cd,ce,cf;
  uint32_t d0,d1,d2,d3,d4,d5,d6,d7,d8,d9,da,db,dc,dd,de,df;
  GK(0, c0, d0)   GK(1, c1, d1)   GK(2, c2, d2)   GK(3, c3, d3)
  GK(4, c4, d4)   GK(5, c5, d5)   GK(6, c6, d6)   GK(7, c7, d7)
  GK(8, c8, d8)   GK(9, c9, d9)   GK(10, ca, da)  GK(11, cb, db)
  GK(12, cc, dc)  GK(13, cd, dd)  GK(14, ce, de)  GK(15, cf, df)
  __syncthreads();   // uh2/vh2 init visible

  float uf0 = uinit, uf1 = uinit, vf0 = 1.0f, vf1 = 1.0f;
  const uint4* exch = (const uint4*)(vh2 + 16 * bq);   // v-quarter, 4x b128
  const uint4* exchU = (const uint4*)(uh2 + 16 * bq);

  for (int it = 0; it < 100; ++it) {
    float om = (it < 2) ? 1.0f : 1.5f;   // plain first 2 iters, then over-relax
    // row sweep: w = K v ; u <- u * (u*w + 1e-8)^{-om}
    uint4 V0 = exch[0], V1 = exch[1], V2 = exch[2], V3 = exch[3];
    float w0a = 0.f, w0b = 0.f, w1a = 0.f, w1b = 0.f;
    FD(a0,V0.x,w0a) FD(a8,V2.x,w0b) FD(b0,V0.x,w1a) FD(b8,V2.x,w1b)
    FD(a1,V0.y,w0a) FD(a9,V2.y,w0b) FD(b1,V0.y,w1a) FD(b9,V2.y,w1b)
    FD(a2,V0.z,w0a) FD(aa,V2.z,w0b) FD(b2,V0.z,w1a) FD(ba,V2.z,w1b)
    FD(a3,V0.w,w0a) FD(ab,V2.w,w0b) FD(b3,V0.w,w1a) FD(bb,V2.w,w1b)
    FD(a4,V1.x,w0a) FD(ac,V3.x,w0b) FD(b4,V1.x,w1a) FD(bc,V3.x,w1b)
    FD(a5,V1.y,w0a) FD(ad,V3.y,w0b) FD(b5,V1.y,w1a) FD(bd,V3.y,w1b)
    FD(a6,V1.z,w0a) FD(ae,V3.z,w0b) FD(b6,V1.z,w1a) FD(be,V3.z,w1b)
    FD(a7,V1.w,w0a) FD(af,V3.w,w0b) FD(b7,V1.w,w1a) FD(bf,V3.w,w1b)
    float w0 = w0a + w0b, w1 = w1a + w1b;
    w0 += __shfl_xor(w0, 1); w0 += __shfl_xor(w0, 2);
    w1 += __shfl_xor(w1, 1); w1 += __shfl_xor(w1, 2);
    float q0 = fmaf(uf0, w0 * 0x1p-8f, 1e-8f);
    float q1 = fmaf(uf1, w1 * 0x1p-8f, 1e-8f);
    uf0 = uf0 * exp2f(-om * __log2f(q0));
    uf1 = uf1 * exp2f(-om * __log2f(q1));
    if (bq == 0) uh2[nh] = pkh2(uf0, uf1);
    __syncthreads();

    // col sweep: z = K^T u ; v <- v * (v*z + 1e-8)^{-om}; exit on |colsum-1|
    uint4 U0 = exchU[0], U1 = exchU[1], U2 = exchU[2], U3 = exchU[3];
    float z0a = 0.f, z0b = 0.f, z1a = 0.f, z1b = 0.f;
    FD(c0,U0.x,z0a) FD(c8,U2.x,z0b) FD(d0,U0.x,z1a) FD(d8,U2.x,z1b)
    FD(c1,U0.y,z0a) FD(c9,U2.y,z0b) FD(d1,U0.y,z1a) FD(d9,U2.y,z1b)
    FD(c2,U0.z,z0a) FD(ca,U2.z,z0b) FD(d2,U0.z,z1a) FD(da,U2.z,z1b)
    FD(c3,U0.w,z0a) FD(cb,U2.w,z0b) FD(d3,U0.w,z1a) FD(db,U2.w,z1b)
    FD(c4,U1.x,z0a) FD(cc,U3.x,z0b) FD(d4,U1.x,z1a) FD(dc,U3.x,z1b)
    FD(c5,U1.y,z0a) FD(cd,U3.y,z0b) FD(d5,U1.y,z1a) FD(dd,U3.y,z1b)
    FD(c6,U1.z,z0a) FD(ce,U3.z,z0b) FD(d6,U1.z,z1a) FD(de,U3.z,z1b)
    FD(c7,U1.w,z0a) FD(cf,U3.w,z0b) FD(d7,U1.w,z1a) FD(df,U3.w,z1b)
    float z0 = z0a + z0b, z1 = z1a + z1b;
    z0 += __shfl_xor(z0, 1); z0 += __shfl_xor(z0, 2);
    z1 += __shfl_xor(z1, 1); z1 += __shfl_xor(z1, 2);
    float e0 = fmaf(vf0, z0 * 0x1p-8f, 1e-8f);
    float e1 = fmaf(vf1, z1 * 0x1p-8f, 1e-8f);
    vf0 = vf0 * exp2f(-om * __log2f(e0));
    vf1 = vf1 * exp2f(-om * __log2f(e1));
    if (bq == 0) vh2[nh] = pkh2(vf0, vf1);
    // convergence flag: one v_cmp + exec test per wave (no shfl chain)
    float dev = fmaxf(fabsf(e0 - 1.0f), fabsf(e1 - 1.0f));
    int wconv = __all(dev < 4e-3f);
    if (l == 0) red[4 + w] = wconv ? 0.f : 1.f;
    __syncthreads();
    float bd = (red[4] + red[5]) + (red[6] + red[7]);
    if (bd == 0.f) break;   // contraction: remaining updates shift T by O(dev)
  }

  // distance = sum u K v * cost_n ; cost_n = 0.1*ln2*(8 - log2(K'))
  {
    uint4 V0 = exch[0], V1 = exch[1], V2 = exch[2], V3 = exch[3];
    float acc0 = 0.f, acc1 = 0.f;
    DST(a0,b0,V0.x) DST(a1,b1,V0.y) DST(a2,b2,V0.z) DST(a3,b3,V0.w)
    DST(a4,b4,V1.x) DST(a5,b5,V1.y) DST(a6,b6,V1.z) DST(a7,b7,V1.w)
    DST(a8,b8,V2.x) DST(a9,b9,V2.y) DST(aa,ba,V2.z) DST(ab,bb,V2.w)
    DST(ac,bc,V3.x) DST(ad,bd,V3.y) DST(ae,be,V3.z) DST(af,bf,V3.w)
    float tot = (uf0 * acc0 + uf1 * acc1) * (0.069314718055994531f * 0x1p-8f);
#pragma unroll
    for (int msk = 1; msk < 64; msk <<= 1) tot += __shfl_xor(tot, msk);
    if (l == 0) red[w] = tot;
    __syncthreads();
    if (t == 0) ws[8194 + b] = (red[0] + red[1]) + (red[2] + red[3]);
  }
}

// ---------------- Phase D: minmax(d) -> similarity -> CE loss ------------------------
__global__ void phaseD(const float* __restrict__ ws, float* __restrict__ out) {
  __shared__ float sim[4096];
  __shared__ float red[16];
  int t = threadIdx.x;
  const float* d = ws + 8194;
  float dv[16];
  float mn = 1e30f, mx = -1e30f;
#pragma unroll
  for (int k = 0; k < 16; ++k) {
    dv[k] = d[k * 256 + t];
    mn = fminf(mn, dv[k]);
    mx = fmaxf(mx, dv[k]);
  }
#pragma unroll
  for (int msk = 1; msk < 64; msk <<= 1) {
    mn = fminf(mn, __shfl_xor(mn, msk));
    mx = fmaxf(mx, __shfl_xor(mx, msk));
  }
  if ((t & 63) == 0) { red[t >> 6] = mn; red[8 + (t >> 6)] = mx; }
  __syncthreads();
  mn = fminf(fminf(red[0], red[1]), fminf(red[2], red[3]));
  mx = fmaxf(fmaxf(red[8], red[9]), fmaxf(red[10], red[11]));
  float inv = 1.0f / (mx - mn);
#pragma unroll
  for (int k = 0; k < 16; ++k) {
    int idx = k * 256 + t;
    float s = expf(-(dv[k] - mn) * inv);
    sim[idx] = s;
    out[1 + idx] = s;
  }
  __syncthreads();
  {
    // parallel LSE: 4 threads per row, 16 serial expf each
    int r = t >> 2, g = t & 3;
    float a = 0.f;
#pragma unroll
    for (int j = 0; j < 16; ++j) a += expf(sim[r * 64 + g * 16 + j]);
    a += __shfl_xor(a, 1);
    a += __shfl_xor(a, 2);
    float val = (g == 0) ? (logf(a) - sim[r * 64 + r]) : 0.f;
#pragma unroll
    for (int msk = 4; msk < 64; msk <<= 1) val += __shfl_xor(val, msk);
    if ((t & 63) == 0) red[12 + (t >> 6)] = val;
    __syncthreads();
    if (t == 0)
      out[0] = ((red[12] + red[13]) + (red[14] + red[15])) * (1.0f / 64.0f);
  }
}

extern "C" void kernel_launch(void* const* d_in, const int* in_sizes, int n_in,
                              void* d_out, int out_size, void* d_ws, size_t ws_size,
                              hipStream_t stream) {
  const float* eeg  = (const float*)d_in[0];
  const float* text = (const float*)d_in[1];
  float* out = (float*)d_out;
  float* ws  = (float*)d_ws;   // needs 12290 floats = 49160 B

  phaseA<<<4096, 256, 33824, stream>>>(eeg, text, ws);
  phaseB<<<1, 256, 0, stream>>>(ws);
  phaseC<<<4096, 256, 34336, stream>>>(eeg, text, ws);
  phaseD<<<1, 256, 0, stream>>>(ws, out);
}

// Round 11
// 170.193 us; speedup vs baseline: 1.0210x; 1.0210x over previous
//
#include <hip/hip_runtime.h>
#include <stdint.h>
#include <math.h>

// OptimalTransportLoss: b=64 pairs^2, n=128, d=128.
// ws floats: [0]=cost_min, [1]=cost_span, [2..8193]=per-block sq min/max pairs,
//            [8194..12289]=distances per (i,j) block.
//
// LDS (bytes): [0,16384) eL (128 rows x 32 u32 fp16-pairs, d-half)  } overlaid
//              [16384,32768) tL                                     } by Kh
//              [32768,33280) e2a | [33280,33792) t2a
//   phaseA: [33792,33824) red                       -> 33824 total
//   phaseC: [33792,34048) vh2 | [34048,34304) uh2 | [34304,34336) red -> 34336

typedef _Float16 h2 __attribute__((ext_vector_type(2)));
typedef _Float16 h8v __attribute__((ext_vector_type(8)));
typedef float f4v __attribute__((ext_vector_type(4)));

__device__ __forceinline__ h2 bch2(uint32_t u) { return __builtin_bit_cast(h2, u); }
__device__ __forceinline__ uint32_t pkh2(float x, float y) {
  h2 h = {(_Float16)x, (_Float16)y};
  return __builtin_bit_cast(uint32_t, h);
}
__device__ __forceinline__ float rnd16(float x) { return (float)(_Float16)x; }
__device__ __forceinline__ float fdot2f(h2 a, h2 b, float c) {
  return __builtin_amdgcn_fdot2(a, b, c, false);
}
// Quad butterfly adds via DPP (single VALU mov_dpp + add; replaces ds-path shfl).
__device__ __forceinline__ float dppadd1(float x) {  // x += lane^1
  int v = __builtin_amdgcn_mov_dpp(__builtin_bit_cast(int, x), 0xB1, 0xF, 0xF, true);
  return x + __builtin_bit_cast(float, v);
}
__device__ __forceinline__ float dppadd2(float x) {  // x += lane^2
  int v = __builtin_amdgcn_mov_dpp(__builtin_bit_cast(int, x), 0x4E, 0xF, 0xF, true);
  return x + __builtin_bit_cast(float, v);
}
// per-row LDS swizzle (u32-index XOR within a 32-u32 row): optimal b128 frag reads
__device__ __forceinline__ int swz(int r) { return ((r & 7) << 2) ^ ((r & 8) << 1); }

// Stage d-half p (cols 64p..64p+63) of eeg[i], text[j] into LDS as fp16 pairs.
__device__ __forceinline__ void stageHalf(const float* __restrict__ ep,
                                          const float* __restrict__ tp,
                                          uint32_t* eL, uint32_t* tL, int t, int p) {
  const float4* e4 = (const float4*)ep;
  const float4* t4 = (const float4*)tp;
#pragma unroll
  for (int k = 0; k < 8; ++k) {
    int F = k * 256 + t;          // 0..2047
    int m = F >> 4, g = F & 15;   // row, float4-group within half
    int src = m * 32 + 16 * p + g;
    int idx = m * 32 + ((2 * g) ^ swz(m));   // even; +1 adjacent (swz has no bit0)
    float4 x = e4[src];
    *(uint2*)(eL + idx) = make_uint2(pkh2(x.x, x.y), pkh2(x.z, x.w));
    float4 y = t4[src];
    *(uint2*)(tL + idx) = make_uint2(pkh2(y.x, y.y), pkh2(y.z, y.w));
  }
}

// fp16 squared-norm partial for this thread's row over one half (order-stable).
__device__ __forceinline__ void normPartial(const uint32_t* eL, const uint32_t* tL,
                                            int t, float& a0, float& a1) {
  int r = t & 127;
  const uint32_t* base = ((t < 128) ? eL : tL) + r * 32;
  int sw = swz(r);
#pragma unroll
  for (int kl = 0; kl < 16; ++kl) {
    uint2 u = *(const uint2*)(base + ((2 * kl) ^ sw));
    h2 x = bch2(u.x), y = bch2(u.y);
    a0 = fdot2f(x, x, a0);
    a1 = fdot2f(y, y, a1);
  }
}

// MFMA build over one d-half (2 k-steps of 32). Wave w owns C rows 32w..32w+31.
// C/D map (m89-verified): value j of acc -> row 16*(2w+i)+4*lg+j, col 16*tc+lr.
__device__ __forceinline__ void buildMfma(const uint32_t* eL, const uint32_t* tL,
                                          int w, int lr, int lg, f4v (&acc)[2][8]) {
#pragma unroll
  for (int ks = 0; ks < 2; ++ks) {
    int off = ks * 16 + lg * 4;
    int r0 = 32 * w + lr, r1 = r0 + 16;
    h8v A0 = *(const h8v*)(eL + r0 * 32 + (off ^ swz(r0)));
    h8v A1 = *(const h8v*)(eL + r1 * 32 + (off ^ swz(r1)));
#pragma unroll
    for (int tg = 0; tg < 2; ++tg) {
      h8v B[4];
#pragma unroll
      for (int q = 0; q < 4; ++q) {
        int rt = (4 * tg + q) * 16 + lr;
        B[q] = *(const h8v*)(tL + rt * 32 + (off ^ swz(rt)));
      }
#pragma unroll
      for (int q = 0; q < 4; ++q) {
        acc[0][4 * tg + q] = __builtin_amdgcn_mfma_f32_16x16x32_f16(A0, B[q], acc[0][4 * tg + q], 0, 0, 0);
        acc[1][4 * tg + q] = __builtin_amdgcn_mfma_f32_16x16x32_f16(A1, B[q], acc[1][4 * tg + q], 0, 0, 0);
      }
    }
  }
}

// ---------------- Phase A: per-block min/max of sq (pre-sqrt, monotone) -------------
// waves_per_eu(3,4): 64 AGPR acc + ~100 arch VGPR fits the 170-reg budget, no spill.
__attribute__((amdgpu_waves_per_eu(3, 4)))
__global__ __launch_bounds__(256) void phaseA(const float* __restrict__ eeg,
                                              const float* __restrict__ text,
                                              float* __restrict__ ws) {
  extern __shared__ char smem[];
  uint32_t* eL = (uint32_t*)smem;
  uint32_t* tL = (uint32_t*)(smem + 16384);
  float* e2a   = (float*)(smem + 32768);
  float* t2a   = (float*)(smem + 33280);
  float* red   = (float*)(smem + 33792);
  int t = threadIdx.x, b = blockIdx.x;
  const float* ep = eeg + (size_t)(b >> 6) * 16384;
  const float* tp = text + (size_t)(b & 63) * 16384;

  int w = t >> 6, lr = t & 15, lg = (t >> 4) & 3;
  f4v acc[2][8];
#pragma unroll
  for (int i = 0; i < 2; ++i)
#pragma unroll
    for (int tc = 0; tc < 8; ++tc) acc[i][tc] = (f4v){0.f, 0.f, 0.f, 0.f};
  float na0 = 0.f, na1 = 0.f;

  stageHalf(ep, tp, eL, tL, t, 0);
  __syncthreads();
  normPartial(eL, tL, t, na0, na1);
  buildMfma(eL, tL, w, lr, lg, acc);
  __syncthreads();
  stageHalf(ep, tp, eL, tL, t, 1);
  __syncthreads();
  normPartial(eL, tL, t, na0, na1);
  {
    int r = t & 127;
    float nn = rnd16(na0 + na1);
    if (t < 128) e2a[r] = nn; else t2a[r] = nn;
  }
  buildMfma(eL, tL, w, lr, lg, acc);
  __syncthreads();

  float e2x[2][4], t2x[8];
#pragma unroll
  for (int i = 0; i < 2; ++i)
#pragma unroll
    for (int j = 0; j < 4; ++j) e2x[i][j] = e2a[32 * w + 16 * i + 4 * lg + j];
#pragma unroll
  for (int tc = 0; tc < 8; ++tc) t2x[tc] = t2a[16 * tc + lr];

  // min/max over raw sq (clamp to 0 hoisted to the end: min/max commute with max(.,0))
  float smn = 1e30f, smx = -1e30f;
#pragma unroll
  for (int i = 0; i < 2; ++i)
#pragma unroll
    for (int tc = 0; tc < 8; ++tc)
#pragma unroll
      for (int j = 0; j < 4; ++j) {
        float sq = fmaf(-2.0f, rnd16(acc[i][tc][j]), e2x[i][j] + t2x[tc]);
        smn = fminf(smn, sq);
        smx = fmaxf(smx, sq);
      }
#pragma unroll
  for (int msk = 1; msk < 64; msk <<= 1) {
    smn = fminf(smn, __shfl_xor(smn, msk));
    smx = fmaxf(smx, __shfl_xor(smx, msk));
  }
  if ((t & 63) == 0) { red[t >> 6] = smn; red[4 + (t >> 6)] = smx; }
  __syncthreads();
  if (t == 0) {
    float mn = fminf(fminf(red[0], red[1]), fminf(red[2], red[3]));
    float mx = fmaxf(fmaxf(red[4], red[5]), fmaxf(red[6], red[7]));
    ws[2 + 2 * b] = fmaxf(mn, 0.0f);   // hoisted clamp (bit-exact, monotone)
    ws[3 + 2 * b] = fmaxf(mx, 0.0f);
  }
}

// ---------------- Phase B: reduce 4096 block min/max -> cost_min, cost_span ---------
__global__ void phaseB(float* __restrict__ ws) {
  __shared__ float red[16];
  int t = threadIdx.x;
  float mn = 1e30f, mx = -1e30f;
#pragma unroll
  for (int k = 0; k < 16; ++k) {
    int idx = k * 256 + t;
    mn = fminf(mn, ws[2 + 2 * idx]);
    mx = fmaxf(mx, ws[3 + 2 * idx]);
  }
#pragma unroll
  for (int msk = 1; msk < 64; msk <<= 1) {
    mn = fminf(mn, __shfl_xor(mn, msk));
    mx = fmaxf(mx, __shfl_xor(mx, msk));
  }
  if ((t & 63) == 0) { red[t >> 6] = mn; red[8 + (t >> 6)] = mx; }
  __syncthreads();
  if (t == 0) {
    mn = fminf(fminf(red[0], red[1]), fminf(red[2], red[3]));
    mx = fmaxf(fmaxf(red[8], red[9]), fmaxf(red[10], red[11]));
    float cmn = rnd16(sqrtf(rnd16(mn)));
    float cmx = rnd16(sqrtf(rnd16(mx)));
    ws[0] = cmn;
    ws[1] = cmx - cmn;
  }
}

// ---- hot-loop helper macros (named registers only, no private arrays) --------------
#define FD(A, V, ACC) ACC = fdot2f(bch2(A), bch2(V), ACC);
#define GK(KI, CV, DV) { \
    int r0_ = 32 * bq + 2 * (KI); int rh_ = 16 * bq + (KI); \
    uint32_t g0_ = Kh[r0_ * 64 + (((cgk + rh_) & 15) * 4 + pos4)]; \
    uint32_t g1_ = Kh[(r0_ + 1) * 64 + (((cgk + rh_) & 15) * 4 + pos4)]; \
    CV = __builtin_amdgcn_perm(g1_, g0_, 0x05040100u); \
    DV = __builtin_amdgcn_perm(g1_, g0_, 0x07060302u); }
#define DST(AK, BK, VK) { \
    h2 vp_ = bch2(VK), K0_ = bch2(AK), K1_ = bch2(BK); float kf_, vf_; \
    kf_ = (float)K0_[0]; vf_ = (float)vp_[0]; acc0 += kf_ * vf_ * (8.0f - __log2f(kf_)); \
    kf_ = (float)K0_[1]; vf_ = (float)vp_[1]; acc0 += kf_ * vf_ * (8.0f - __log2f(kf_)); \
    kf_ = (float)K1_[0]; vf_ = (float)vp_[0]; acc1 += kf_ * vf_ * (8.0f - __log2f(kf_)); \
    kf_ = (float)K1_[1]; vf_ = (float)vp_[1]; acc1 += kf_ * vf_ * (8.0f - __log2f(kf_)); }

// ---------------- Phase C: MFMA cost build + register-resident Sinkhorn -------------
// K' = 2^8 * exp(-(c-cmn)/(0.1*span)) stored fp16 (all normal: [0.0116,256]).
// Early exit: max|colsum-1| < 4e-3. Convergence is transient-dominated (~17 iters;
// dur invariant across tol 1e-3..4e-3 and under over-relaxation — both measured null).
__attribute__((amdgpu_waves_per_eu(3, 4)))
__global__ __launch_bounds__(256) void phaseC(const float* __restrict__ eeg,
                                              const float* __restrict__ text,
                                              float* __restrict__ ws) {
  extern __shared__ char smem[];
  uint32_t* eL  = (uint32_t*)smem;
  uint32_t* tL  = (uint32_t*)(smem + 16384);
  uint32_t* Kh  = (uint32_t*)smem;              // 8192 u32 overlay
  float* e2a    = (float*)(smem + 32768);
  float* t2a    = (float*)(smem + 33280);
  uint32_t* vh2 = (uint32_t*)(smem + 33792);
  uint32_t* uh2 = (uint32_t*)(smem + 34048);
  float* red    = (float*)(smem + 34304);
  int t = threadIdx.x, b = blockIdx.x;
  const float* ep = eeg + (size_t)(b >> 6) * 16384;
  const float* tp = text + (size_t)(b & 63) * 16384;

  int w = t >> 6, lr = t & 15, lg = (t >> 4) & 3;
  f4v acc[2][8];
#pragma unroll
  for (int i = 0; i < 2; ++i)
#pragma unroll
    for (int tc = 0; tc < 8; ++tc) acc[i][tc] = (f4v){0.f, 0.f, 0.f, 0.f};
  float na0 = 0.f, na1 = 0.f;

  stageHalf(ep, tp, eL, tL, t, 0);
  __syncthreads();
  normPartial(eL, tL, t, na0, na1);
  buildMfma(eL, tL, w, lr, lg, acc);
  __syncthreads();
  stageHalf(ep, tp, eL, tL, t, 1);
  __syncthreads();
  normPartial(eL, tL, t, na0, na1);
  {
    int r = t & 127;
    float nn = rnd16(na0 + na1);
    if (t < 128) e2a[r] = nn; else t2a[r] = nn;
  }
  buildMfma(eL, tL, w, lr, lg, acc);
  __syncthreads();   // eL/tL reads done; e2a/t2a visible; Kh overlay now safe

  float cmn = ws[0];
  float kexp2 = 1.4426950408889634f / (0.1f * ws[1]);  // log2e/(reg*span)

  float e2x[2][4], t2x[8];
#pragma unroll
  for (int i = 0; i < 2; ++i)
#pragma unroll
    for (int j = 0; j < 4; ++j) e2x[i][j] = e2a[32 * w + 16 * i + 4 * lg + j];
#pragma unroll
  for (int tc = 0; tc < 8; ++tc) t2x[tc] = t2a[16 * tc + lr];

  // K-build: per element -> fp16 bits into Kh with rotation swizzle
  //   pos(hc,row) = (((hc>>2)+(row>>1))&15)*4 + (hc&3), hc = col>>1
  uint16_t* Kh16 = (uint16_t*)Kh;
  float ks = 0.f;
#pragma unroll
  for (int i = 0; i < 2; ++i)
#pragma unroll
    for (int tc = 0; tc < 8; ++tc)
#pragma unroll
      for (int j = 0; j < 4; ++j) {
        int row = 32 * w + 16 * i + 4 * lg + j;
        int col = 16 * tc + lr;
        float ip = rnd16(acc[i][tc][j]);
        float sq = fmaxf(fmaf(-2.0f, ip, e2x[i][j] + t2x[tc]), 0.0f);
        float c  = rnd16(sqrtf(rnd16(sq)));
        float kf = exp2f(fmaf(cmn - c, kexp2, 8.0f));   // 2^8-scaled kernel
        ks += kf;
        int hc = col >> 1;
        int pos = (((hc >> 2) + (row >> 1)) & 15) * 4 + (hc & 3);
        Kh16[(row * 64 + pos) * 2 + (col & 1)] = __builtin_bit_cast(uint16_t, (_Float16)kf);
      }
#pragma unroll
  for (int msk = 1; msk < 64; msk <<= 1) ks += __shfl_xor(ks, msk);
  if ((t & 63) == 0) red[t >> 6] = ks;
  __syncthreads();
  float Sp = (red[0] + red[1]) + (red[2] + red[3]);   // = 256 * sum(K)
  float uinit = 256.0f / Sp;                           // = 1/sum(K)
  if (t < 64) { vh2[t] = 0x3C003C00u; uh2[t] = pkh2(uinit, uinit); }

  // Register K tiles as NAMED registers.
  // Lane (w,la,bq): rows n0,n0+1 (aN/bN), cols 2nh,2nh+1 (cN/dN).
  int l = t & 63, la = l >> 2, bq = l & 3;
  int n0 = 32 * w + 2 * la;
  int nh = 16 * w + la;
  int cgk = nh >> 2, pos4 = la & 3;
  uint32_t a0,a1,a2,a3,a4,a5,a6,a7,a8,a9,aa,ab,ac,ad,ae,af;
  uint32_t b0,b1,b2,b3,b4,b5,b6,b7,b8,b9,ba,bb,bc,bd,be,bf;
  {
    int g0 = (4 * bq + 0 + nh) & 15, g1 = (4 * bq + 1 + nh) & 15;
    int g2 = (4 * bq + 2 + nh) & 15, g3 = (4 * bq + 3 + nh) & 15;
    uint4 X;
    X = *(const uint4*)(Kh + n0 * 64 + g0 * 4); a0 = X.x; a1 = X.y; a2 = X.z; a3 = X.w;
    X = *(const uint4*)(Kh + n0 * 64 + g1 * 4); a4 = X.x; a5 = X.y; a6 = X.z; a7 = X.w;
    X = *(const uint4*)(Kh + n0 * 64 + g2 * 4); a8 = X.x; a9 = X.y; aa = X.z; ab = X.w;
    X = *(const uint4*)(Kh + n0 * 64 + g3 * 4); ac = X.x; ad = X.y; ae = X.z; af = X.w;
    X = *(const uint4*)(Kh + (n0 + 1) * 64 + g0 * 4); b0 = X.x; b1 = X.y; b2 = X.z; b3 = X.w;
    X = *(const uint4*)(Kh + (n0 + 1) * 64 + g1 * 4); b4 = X.x; b5 = X.y; b6 = X.z; b7 = X.w;
    X = *(const uint4*)(Kh + (n0 + 1) * 64 + g2 * 4); b8 = X.x; b9 = X.y; ba = X.z; bb = X.w;
    X = *(const uint4*)(Kh + (n0 + 1) * 64 + g3 * 4); bc = X.x; bd = X.y; be = X.z; bf = X.w;
  }
  uint32_t c0,c1,c2,c3,c4,c5,c6,c7,c8,c9,ca,cb,cc,cd,ce,cf;
  uint32_t d0,d1,d2,d3,d4,d5,d6,d7,d8,d9,da,db,dc,dd,de,df;
  GK(0, c0, d0)   GK(1, c1, d1)   GK(2, c2, d2)   GK(3, c3, d3)
  GK(4, c4, d4)   GK(5, c5, d5)   GK(6, c6, d6)   GK(7, c7, d7)
  GK(8, c8, d8)   GK(9, c9, d9)   GK(10, ca, da)  GK(11, cb, db)
  GK(12, cc, dc)  GK(13, cd, dd)  GK(14, ce, de)  GK(15, cf, df)
  __syncthreads();   // uh2/vh2 init visible

  float uf0 = uinit, uf1 = uinit, vf0 = 1.0f, vf1 = 1.0f;
  const uint4* exch = (const uint4*)(vh2 + 16 * bq);   // v-quarter, 4x b128
  const uint4* exchU = (const uint4*)(uh2 + 16 * bq);

  for (int it = 0; it < 100; ++it) {
    // row sweep: w = K v ; u <- u / (u*w + 1e-8)
    uint4 V0 = exch[0], V1 = exch[1], V2 = exch[2], V3 = exch[3];
    float w0a = 0.f, w0b = 0.f, w1a = 0.f, w1b = 0.f;
    FD(a0,V0.x,w0a) FD(a8,V2.x,w0b) FD(b0,V0.x,w1a) FD(b8,V2.x,w1b)
    FD(a1,V0.y,w0a) FD(a9,V2.y,w0b) FD(b1,V0.y,w1a) FD(b9,V2.y,w1b)
    FD(a2,V0.z,w0a) FD(aa,V2.z,w0b) FD(b2,V0.z,w1a) FD(ba,V2.z,w1b)
    FD(a3,V0.w,w0a) FD(ab,V2.w,w0b) FD(b3,V0.w,w1a) FD(bb,V2.w,w1b)
    FD(a4,V1.x,w0a) FD(ac,V3.x,w0b) FD(b4,V1.x,w1a) FD(bc,V3.x,w1b)
    FD(a5,V1.y,w0a) FD(ad,V3.y,w0b) FD(b5,V1.y,w1a) FD(bd,V3.y,w1b)
    FD(a6,V1.z,w0a) FD(ae,V3.z,w0b) FD(b6,V1.z,w1a) FD(be,V3.z,w1b)
    FD(a7,V1.w,w0a) FD(af,V3.w,w0b) FD(b7,V1.w,w1a) FD(bf,V3.w,w1b)
    float w0 = w0a + w0b, w1 = w1a + w1b;
    w0 = dppadd2(dppadd1(w0));
    w1 = dppadd2(dppadd1(w1));
    float q0 = fmaf(uf0, w0 * 0x1p-8f, 1e-8f);
    float q1 = fmaf(uf1, w1 * 0x1p-8f, 1e-8f);
    uf0 = uf0 * __builtin_amdgcn_rcpf(q0);
    uf1 = uf1 * __builtin_amdgcn_rcpf(q1);
    if (bq == 0) uh2[nh] = pkh2(uf0, uf1);
    __syncthreads();

    // col sweep: z = K^T u ; v <- v / (v*z + 1e-8); early-exit on |colsum-1|
    uint4 U0 = exchU[0], U1 = exchU[1], U2 = exchU[2], U3 = exchU[3];
    float z0a = 0.f, z0b = 0.f, z1a = 0.f, z1b = 0.f;
    FD(c0,U0.x,z0a) FD(c8,U2.x,z0b) FD(d0,U0.x,z1a) FD(d8,U2.x,z1b)
    FD(c1,U0.y,z0a) FD(c9,U2.y,z0b) FD(d1,U0.y,z1a) FD(d9,U2.y,z1b)
    FD(c2,U0.z,z0a) FD(ca,U2.z,z0b) FD(d2,U0.z,z1a) FD(da,U2.z,z1b)
    FD(c3,U0.w,z0a) FD(cb,U2.w,z0b) FD(d3,U0.w,z1a) FD(db,U2.w,z1b)
    FD(c4,U1.x,z0a) FD(cc,U3.x,z0b) FD(d4,U1.x,z1a) FD(dc,U3.x,z1b)
    FD(c5,U1.y,z0a) FD(cd,U3.y,z0b) FD(d5,U1.y,z1a) FD(dd,U3.y,z1b)
    FD(c6,U1.z,z0a) FD(ce,U3.z,z0b) FD(d6,U1.z,z1a) FD(de,U3.z,z1b)
    FD(c7,U1.w,z0a) FD(cf,U3.w,z0b) FD(d7,U1.w,z1a) FD(df,U3.w,z1b)
    float z0 = z0a + z0b, z1 = z1a + z1b;
    z0 = dppadd2(dppadd1(z0));
    z1 = dppadd2(dppadd1(z1));
    float e0 = fmaf(vf0, z0 * 0x1p-8f, 1e-8f);
    float e1 = fmaf(vf1, z1 * 0x1p-8f, 1e-8f);
    vf0 = vf0 * __builtin_amdgcn_rcpf(e0);
    vf1 = vf1 * __builtin_amdgcn_rcpf(e1);
    if (bq == 0) vh2[nh] = pkh2(vf0, vf1);
    // convergence flag: one v_cmp + exec test per wave (no shfl chain)
    float dev = fmaxf(fabsf(e0 - 1.0f), fabsf(e1 - 1.0f));
    int wconv = __all(dev < 4e-3f);
    if (l == 0) red[4 + w] = wconv ? 0.f : 1.f;
    __syncthreads();
    float bd = (red[4] + red[5]) + (red[6] + red[7]);
    if (bd == 0.f) break;   // contraction: remaining updates shift T by O(dev)
  }

  // distance = sum u K v * cost_n ; cost_n = 0.1*ln2*(8 - log2(K'))
  {
    uint4 V0 = exch[0], V1 = exch[1], V2 = exch[2], V3 = exch[3];
    float acc0 = 0.f, acc1 = 0.f;
    DST(a0,b0,V0.x) DST(a1,b1,V0.y) DST(a2,b2,V0.z) DST(a3,b3,V0.w)
    DST(a4,b4,V1.x) DST(a5,b5,V1.y) DST(a6,b6,V1.z) DST(a7,b7,V1.w)
    DST(a8,b8,V2.x) DST(a9,b9,V2.y) DST(aa,ba,V2.z) DST(ab,bb,V2.w)
    DST(ac,bc,V3.x) DST(ad,bd,V3.y) DST(ae,be,V3.z) DST(af,bf,V3.w)
    float tot = (uf0 * acc0 + uf1 * acc1) * (0.069314718055994531f * 0x1p-8f);
#pragma unroll
    for (int msk = 1; msk < 64; msk <<= 1) tot += __shfl_xor(tot, msk);
    if (l == 0) red[w] = tot;
    __syncthreads();
    if (t == 0) ws[8194 + b] = (red[0] + red[1]) + (red[2] + red[3]);
  }
}

// ---------------- Phase D: minmax(d) -> similarity -> CE loss ------------------------
__global__ void phaseD(const float* __restrict__ ws, float* __restrict__ out) {
  __shared__ float sim[4096];
  __shared__ float red[16];
  int t = threadIdx.x;
  const float* d = ws + 8194;
  float dv[16];
  float mn = 1e30f, mx = -1e30f;
#pragma unroll
  for (int k = 0; k < 16; ++k) {
    dv[k] = d[k * 256 + t];
    mn = fminf(mn, dv[k]);
    mx = fmaxf(mx, dv[k]);
  }
#pragma unroll
  for (int msk = 1; msk < 64; msk <<= 1) {
    mn = fminf(mn, __shfl_xor(mn, msk));
    mx = fmaxf(mx, __shfl_xor(mx, msk));
  }
  if ((t & 63) == 0) { red[t >> 6] = mn; red[8 + (t >> 6)] = mx; }
  __syncthreads();
  mn = fminf(fminf(red[0], red[1]), fminf(red[2], red[3]));
  mx = fmaxf(fmaxf(red[8], red[9]), fmaxf(red[10], red[11]));
  float inv = 1.0f / (mx - mn);
#pragma unroll
  for (int k = 0; k < 16; ++k) {
    int idx = k * 256 + t;
    float s = expf(-(dv[k] - mn) * inv);
    sim[idx] = s;
    out[1 + idx] = s;
  }
  __syncthreads();
  {
    // parallel LSE: 4 threads per row, 16 serial expf each
    int r = t >> 2, g = t & 3;
    float a = 0.f;
#pragma unroll
    for (int j = 0; j < 16; ++j) a += expf(sim[r * 64 + g * 16 + j]);
    a += __shfl_xor(a, 1);
    a += __shfl_xor(a, 2);
    float val = (g == 0) ? (logf(a) - sim[r * 64 + r]) : 0.f;
#pragma unroll
    for (int msk = 4; msk < 64; msk <<= 1) val += __shfl_xor(val, msk);
    if ((t & 63) == 0) red[12 + (t >> 6)] = val;
    __syncthreads();
    if (t == 0)
      out[0] = ((red[12] + red[13]) + (red[14] + red[15])) * (1.0f / 64.0f);
  }
}

extern "C" void kernel_launch(void* const* d_in, const int* in_sizes, int n_in,
                              void* d_out, int out_size, void* d_ws, size_t ws_size,
                              hipStream_t stream) {
  const float* eeg  = (const float*)d_in[0];
  const float* text = (const float*)d_in[1];
  float* out = (float*)d_out;
  float* ws  = (float*)d_ws;   // needs 12290 floats = 49160 B

  phaseA<<<4096, 256, 33824, stream>>>(eeg, text, ws);
  phaseB<<<1, 256, 0, stream>>>(ws);
  phaseC<<<4096, 256, 34336, stream>>>(eeg, text, ws);
  phaseD<<<1, 256, 0, stream>>>(ws, out);
}